// Round 3
// baseline (300.251 us; speedup 1.0000x reference)
//
#include <hip/hip_runtime.h>
#include <math.h>
#include <stdint.h>

// ---------------------------------------------------------------------------
// Mlp_8744553415182 on MI355X (gfx950). FP32 I/O; bf16 MFMA compute.
//   1. prep_kernel:  x->xb(+xpad,s_x), W1->w1b(+w1pad,s_w), W2->w2b, s_b, counts=0
//   2. gemm1_topk:   z=0: h = gelu(x.W1^T+b1) (256x256 tile, K=1024)
//                    z=1: counts[n] += #(x_topk.w1_topk+b1 > 0) (K=128)
//   3. fixup_kernel: channels with counts<=2048 -> exact quantized path
//   4. gemm2_bias:   out = h.W2^T + b2 (256x128 tile, K=4096)
// R8->R9: R8 kept a monolithic stage->bar->read->MFMA->bar chunk (the m196
// "coarse split" that measures -7..-27%). R9 is the m201 8-phase interleave,
// template-faithful: per 128-k iteration, 8 phases of
//   { 8-10 ds_read_b128 (same-phase consumption) | stage ONE 32-k slice via
//     global_load_lds -> s_barrier -> (compiler lgkm waits) -> setprio(1)
//     -> 16 MFMA -> setprio(0) -> [odd phases: s_waitcnt vmcnt(10|8)] ->
//     s_barrier }
// Dead-region stage schedule (slice staged in phase p was last ds_read in
// phase p-1; consumed 6-7 phases later, gated by the odd-phase counted vmcnt
// which NEVER drains to 0 mid-loop):
//   ph0: B(t+1,ks1)  ph1: A(t+2,ks0)  ph2: B(t+2,ks0)  ph3: A(t+2,ks1)
//   ph4: B(t+2,ks1)  ph5: A(t+3,ks0)  ph6: B(t+3,ks0)  ph7: A(t+3,ks1)
// Prologue = 7 slices (ages mimic virtual phases 1..7), peel = last tile pair
// (only ph0's B-stage; tail waits 8->4->0). Frag regs A8+B2 (same-phase use)
// keep VGPR+AGPR under the 256/wave 8-wave budget (no scratch => vmcnt ledger
// stays exact). XOR swizzle (R3: 0 conflicts) + slab epilogues kept.
// ---------------------------------------------------------------------------

typedef __bf16 v8bf __attribute__((ext_vector_type(8)));
typedef float v4f __attribute__((ext_vector_type(4)));
typedef unsigned short v8us __attribute__((ext_vector_type(8)));

#define AS_G __attribute__((address_space(1)))
#define AS_L __attribute__((address_space(3)))
#define GLOAD(gp, lp) __builtin_amdgcn_global_load_lds((const AS_G void*)(gp), (AS_L void*)(lp), 16, 0, 0)
#define WAITV(n) asm volatile("s_waitcnt vmcnt(" #n ")" ::: "memory")
#define FENCE() __builtin_amdgcn_sched_barrier(0)
#define BAR() __builtin_amdgcn_s_barrier()

__device__ __forceinline__ unsigned short f2bf(float f) {
    union { float f; unsigned int i; } v; v.f = f;
    unsigned int r = v.i + 0x7fffu + ((v.i >> 16) & 1u);   // RNE
    return (unsigned short)(r >> 16);
}
__device__ __forceinline__ float gelu_fast(float v) {
    float u = v * (0.79788456080286536f + 0.035677408136300125f * v * v);
    u = fminf(fmaxf(u, -15.f), 15.f);
    float e = __expf(2.0f * u);
    return v * e * __builtin_amdgcn_rcpf(e + 1.0f);   // v*e/(e+1) = 0.5v(1+tanh u)
}
__device__ __forceinline__ float gelu_exact(float v) {
    return 0.5f * v * (1.0f + erff(v * 0.70710678118654752440f));
}

// --------------------------- 8-phase deep-pipelined core --------------------
// NB = # of 16-row B blocks (16 -> BN=256 NF=4 FW=2 ; 8 -> BN=128 NF=2 FW=1).
// LDS: 2 tile-buffers (even tiles buf0, odd buf1). Tile buffer = A 32 blocks
// [(rb*2+ks)*512] + B 2*NB blocks [16384 + (nb*2+ks)*512]; block = 16 rows x
// 32 k bf16, XOR-swizzled (writer: lane sources row l>>2, kchunk
// ((l&3)^((l>>3)&3))*8, LDS linear lane*16B; reader roff = R*32+((Q^((R>>1)&3))*8)).
template<int NB>
__device__ __forceinline__ void gemm_core8p(const unsigned short* __restrict__ A,
                                            const unsigned short* __restrict__ Bm,
                                            const int K,
                                            const int bm0, const int bn0,
                                            unsigned short* lds,
                                            v4f (&acc)[8][NB / 4])
{
    constexpr int NF = NB / 4;
    constexpr int FW = NF / 2;
    constexpr int TILE = (32 + 2 * NB) * 512;
    const int tid = threadIdx.x;
    const int wave = tid >> 6, lane = tid & 63;
    const int wm = wave >> 2, wn = wave & 3;
    const int rowInChunk = lane >> 2;
    const int col8 = ((lane & 3) ^ ((lane >> 3) & 3)) * 8;
    const int ldsLane = lane * 8;
    const int R = lane & 15, Q = lane >> 4;
    const int roff = R * 32 + ((Q ^ ((R >> 1) & 3)) * 8);
    const int NT2 = K >> 7;                    // 128-k iterations

    unsigned short* const buf0 = lds;
    unsigned short* const buf1 = lds + TILE;

    const size_t aB0 = (size_t)(bm0 + (2 * wave) * 16 + rowInChunk) * K + col8;
    const size_t aB1 = aB0 + (size_t)16 * K;
    size_t bB0, bB1 = 0;
    if constexpr (NB == 16) {
        bB0 = (size_t)(bn0 + (2 * wave) * 16 + rowInChunk) * K + col8;
        bB1 = bB0 + (size_t)16 * K;
    } else {
        bB0 = (size_t)(bn0 + wave * 16 + rowInChunk) * K + col8;
    }

    v8bf Ar[8];
    v8bf Br[FW];

#define STG_A(tl, ks, bufp) { \
    GLOAD(A + aB0 + (tl) * 64 + (ks) * 32, (bufp) + ((2 * wave) * 2 + (ks)) * 512 + ldsLane); \
    GLOAD(A + aB1 + (tl) * 64 + (ks) * 32, (bufp) + ((2 * wave + 1) * 2 + (ks)) * 512 + ldsLane); }
#define STG_B(tl, ks, bufp) { \
    if constexpr (NB == 16) { \
        GLOAD(Bm + bB0 + (tl) * 64 + (ks) * 32, (bufp) + 16384 + ((2 * wave) * 2 + (ks)) * 512 + ldsLane); \
        GLOAD(Bm + bB1 + (tl) * 64 + (ks) * 32, (bufp) + 16384 + ((2 * wave + 1) * 2 + (ks)) * 512 + ldsLane); \
    } else { \
        GLOAD(Bm + bB0 + (tl) * 64 + (ks) * 32, (bufp) + 16384 + ((wave) * 2 + (ks)) * 512 + ldsLane); } }
#define RD_A(bufp, ks) { _Pragma("unroll") \
    for (int mf = 0; mf < 8; ++mf) \
        Ar[mf] = *(const v8bf*)&(bufp)[((wm * 8 + mf) * 2 + (ks)) * 512 + roff]; }
#define RD_B(bufp, ks, fg) { _Pragma("unroll") \
    for (int nfi = 0; nfi < FW; ++nfi) \
        Br[nfi] = *(const v8bf*)&(bufp)[16384 + ((wn * NF + (fg) * FW + nfi) * 2 + (ks)) * 512 + roff]; }
#define MM(fg) \
    __builtin_amdgcn_s_setprio(1); \
    _Pragma("unroll") for (int mf = 0; mf < 8; ++mf) { \
    _Pragma("unroll") for (int nfi = 0; nfi < FW; ++nfi) \
        acc[mf][(fg) * FW + nfi] = __builtin_amdgcn_mfma_f32_16x16x32_bf16(Ar[mf], Br[nfi], acc[mf][(fg) * FW + nfi], 0, 0, 0); } \
    __builtin_amdgcn_s_setprio(0);
#define MIDB FENCE(); BAR(); FENCE();
#define ENDB FENCE(); BAR(); FENCE();
#define WVS  { if constexpr (NB == 16) { WAITV(10); } else { WAITV(8); } }

    // prologue: 7 slices, ages == virtual phases 1..7 of iteration -1
    STG_A(0, 0, buf0); STG_B(0, 0, buf0); STG_A(0, 1, buf0); STG_B(0, 1, buf0);
    STG_A(1, 0, buf1); STG_B(1, 0, buf1); STG_A(1, 1, buf1);
    WVS;                               // drains slices 0,1 (A0ks0,B0ks0)
    FENCE(); BAR(); FENCE();

    for (int i = 0; i < NT2 - 1; ++i) {
        const int t1 = 2 * i + 1, t2 = 2 * i + 2, t3 = 2 * i + 3;
        // ph0
        RD_A(buf0, 0); RD_B(buf0, 0, 0); STG_B(t1, 1, buf1);
        MIDB; MM(0); ENDB;
        // ph1
        RD_B(buf0, 0, 1); STG_A(t2, 0, buf0);
        MIDB; MM(1); WVS; ENDB;
        // ph2
        RD_A(buf0, 1); RD_B(buf0, 1, 0); STG_B(t2, 0, buf0);
        MIDB; MM(0); ENDB;
        // ph3
        RD_B(buf0, 1, 1); STG_A(t2, 1, buf0);
        MIDB; MM(1); WVS; ENDB;
        // ph4
        RD_A(buf1, 0); RD_B(buf1, 0, 0); STG_B(t2, 1, buf0);
        MIDB; MM(0); ENDB;
        // ph5
        RD_B(buf1, 0, 1); STG_A(t3, 0, buf1);
        MIDB; MM(1); WVS; ENDB;
        // ph6
        RD_A(buf1, 1); RD_B(buf1, 1, 0); STG_B(t3, 0, buf1);
        MIDB; MM(0); ENDB;
        // ph7
        RD_B(buf1, 1, 1); STG_A(t3, 1, buf1);
        MIDB; MM(1); WVS; ENDB;
    }
    // peeled last tile pair (t = NT-2 in buf0, NT-1 in buf1)
    {
        const int tl = NT2 * 2 - 1;    // NT-1
        // ph0 (stages the one missing slice: B(NT-1,ks1))
        RD_A(buf0, 0); RD_B(buf0, 0, 0); STG_B(tl, 1, buf1);
        MIDB; MM(0); ENDB;
        // ph1
        RD_B(buf0, 0, 1);
        MIDB; MM(1); if constexpr (NB == 16) { WAITV(8); } else { WAITV(6); } ENDB;
        // ph2
        RD_A(buf0, 1); RD_B(buf0, 1, 0);
        MIDB; MM(0); ENDB;
        // ph3
        RD_B(buf0, 1, 1);
        MIDB; MM(1); if constexpr (NB == 16) { WAITV(4); } else { WAITV(3); } ENDB;
        // ph4
        RD_A(buf1, 0); RD_B(buf1, 0, 0);
        MIDB; MM(0); ENDB;
        // ph5
        RD_B(buf1, 0, 1);
        MIDB; MM(1); WAITV(0); ENDB;
        // ph6
        RD_A(buf1, 1); RD_B(buf1, 1, 0);
        MIDB; MM(0); ENDB;
        // ph7
        RD_B(buf1, 1, 1);
        MIDB; MM(1); ENDB;
    }
#undef STG_A
#undef STG_B
#undef RD_A
#undef RD_B
#undef MM
#undef MIDB
#undef ENDB
#undef WVS
}

// --------------------------- prep (fused) -----------------------------------
__global__ void prep_kernel(const float* __restrict__ x, const float* __restrict__ W1,
                            const float* __restrict__ W2, const float* __restrict__ b1,
                            unsigned short* __restrict__ xb, unsigned short* __restrict__ w1b,
                            unsigned short* __restrict__ w2b,
                            unsigned short* __restrict__ xpad, unsigned short* __restrict__ w1pad,
                            float* __restrict__ s_x, float* __restrict__ s_w,
                            float* __restrict__ s_b, int* __restrict__ counts)
{
    const int b = blockIdx.x, t = threadIdx.x;
    __shared__ float red[4];

    if (b < 16384) {
        const float* src; unsigned short* dst; unsigned short* pad = nullptr; float* sc = nullptr;
        if (b < 8192)       { src = x  + (size_t)b * 1024;            dst = xb  + (size_t)b * 1024;
                              pad = xpad  + (size_t)b * 128;          sc = s_x + b; }
        else if (b < 12288) { int r = b - 8192;  src = W1 + (size_t)r * 1024; dst = w1b + (size_t)r * 1024;
                              pad = w1pad + (size_t)r * 128;          sc = s_w + r; }
        else                { int r = b - 12288; src = W2 + (size_t)r * 1024; dst = w2b + (size_t)r * 1024; }

        float4 v = ((const float4*)src)[t];
        ushort4 u;
        u.x = f2bf(v.x); u.y = f2bf(v.y); u.z = f2bf(v.z); u.w = f2bf(v.w);
        ((ushort4*)dst)[t] = u;
        if (pad && t < 32) {
            int c = t * 4;
            ushort4 p;
            p.x = (c + 0 < 103) ? u.x : (unsigned short)0;
            p.y = (c + 1 < 103) ? u.y : (unsigned short)0;
            p.z = (c + 2 < 103) ? u.z : (unsigned short)0;
            p.w = (c + 3 < 103) ? u.w : (unsigned short)0;
            ((ushort4*)pad)[t] = p;
        }
        if (sc) {
            float m = fmaxf(fmaxf(fabsf(v.x), fabsf(v.y)), fmaxf(fabsf(v.z), fabsf(v.w)));
#pragma unroll
            for (int off = 32; off; off >>= 1) m = fmaxf(m, __shfl_xor(m, off, 64));
            if ((t & 63) == 0) red[t >> 6] = m;
            __syncthreads();
            if (t == 0) {
                m = fmaxf(fmaxf(red[0], red[1]), fmaxf(red[2], red[3]));
                *sc = fmaxf(m, 1e-5f) * (1.0f / 127.0f);
            }
        }
    } else {
        float m = 0.f;
        for (int k = t; k < 4096; k += 256) { m = fmaxf(m, fabsf(b1[k])); counts[k] = 0; }
#pragma unroll
        for (int off = 32; off; off >>= 1) m = fmaxf(m, __shfl_xor(m, off, 64));
        if ((t & 63) == 0) red[t >> 6] = m;
        __syncthreads();
        if (t == 0) {
            m = fmaxf(fmaxf(red[0], red[1]), fmaxf(red[2], red[3]));
            *s_b = fmaxf(m, 1e-5f) * (1.0f / 127.0f);
        }
    }
}

// --------------------------- gemm1 + topk (fused dispatch) -------------------
// grid (16, 32, 2): x = N-block (XCD = linear%8), y = M-block, z = path.
// 512 threads, 128 KB LDS, 1 block/CU.
__global__ __launch_bounds__(512, 2)
void gemm1_topk(const unsigned short* __restrict__ xb,
                const unsigned short* __restrict__ w1b,
                const unsigned short* __restrict__ xpad,
                const unsigned short* __restrict__ w1pad,
                const float* __restrict__ b1,
                unsigned short* __restrict__ hbuf,
                int* __restrict__ counts)
{
    __shared__ unsigned short lds[65536];   // 128 KB: 2 tile buffers x 64 KB
    v4f acc[8][4];
    v4f z = {0.f, 0.f, 0.f, 0.f};
#pragma unroll
    for (int i = 0; i < 8; ++i)
#pragma unroll
        for (int j = 0; j < 4; ++j) acc[i][j] = z;

    const int bn0 = blockIdx.x * 256, bm0 = blockIdx.y * 256;
    const int tid = threadIdx.x;
    const int lane = tid & 63, wave = tid >> 6;
    const int wm = wave >> 2, wn = wave & 3, q = lane >> 4;

    if (blockIdx.z == 0) {
        gemm_core8p<16>(xb, w1b, 1024, bm0, bn0, lds, acc);

        float bvj[4];
#pragma unroll
        for (int nf = 0; nf < 4; ++nf) bvj[nf] = b1[bn0 + wn * 64 + nf * 16 + (lane & 15)];

        unsigned short* slab = lds;          // 64 x 256 bf16 slab = 32 KB
#pragma unroll
        for (int p = 0; p < 4; ++p) {
            __syncthreads();
            if (wm == (p >> 1)) {
                const int mfb = (p & 1) * 4;
#pragma unroll
                for (int mfp = 0; mfp < 4; ++mfp)
#pragma unroll
                    for (int nf = 0; nf < 4; ++nf) {
                        const int colq = wn * 64 + nf * 16 + (lane & 15);
#pragma unroll
                        for (int r = 0; r < 4; ++r)
                            slab[(mfp * 16 + q * 4 + r) * 256 + colq] =
                                f2bf(gelu_fast(acc[mfb + mfp][nf][r] + bvj[nf]));
                    }
            }
            __syncthreads();
#pragma unroll
            for (int s = 0; s < 4; ++s) {
                const int idx = s * 512 + tid;          // 0..2047
                const int row = idx >> 5, ch = idx & 31;
                *(v8us*)&hbuf[(size_t)(bm0 + p * 64 + row) * 4096 + bn0 + ch * 8] =
                    *(const v8us*)&slab[row * 256 + ch * 8];
            }
        }
    } else {
        gemm_core8p<16>(xpad, w1pad, 128, bm0, bn0, lds, acc);

#pragma unroll
        for (int nf = 0; nf < 4; ++nf) {
            const int n = bn0 + wn * 64 + nf * 16 + (lane & 15);
            const float bv = b1[n];
            int cnt = 0;
#pragma unroll
            for (int mf = 0; mf < 8; ++mf)
#pragma unroll
                for (int r = 0; r < 4; ++r)
                    cnt += (acc[mf][nf][r] + bv > 0.0f) ? 1 : 0;
            cnt += __shfl_xor(cnt, 16, 64);
            cnt += __shfl_xor(cnt, 32, 64);
            if (lane < 16 && cnt) atomicAdd(&counts[n], cnt);
        }
    }
}

// --------------------------- fixup (exact quant path) ------------------------
__global__ void fixup_kernel(const float* __restrict__ x,
                             const float* __restrict__ W1,
                             const float* __restrict__ b1,
                             const int* __restrict__ counts,
                             const float* __restrict__ s_x,
                             const float* __restrict__ s_w,
                             const float* __restrict__ s_b,
                             unsigned short* __restrict__ hbuf)
{
    const int n = blockIdx.x;
    if (counts[n] > 2048) return;   // fp channel: keep gemm1 result
    __shared__ float qw[1024];
    const float swn = s_w[n];
    for (int k = threadIdx.x; k < 1024; k += 256) {
        float q = nearbyintf(W1[(size_t)n * 1024 + k] / swn);
        qw[k] = fminf(fmaxf(q, -128.f), 127.f) * swn;
    }
    __syncthreads();
    const float sb = *s_b;
    const float bq = fminf(fmaxf(nearbyintf(b1[n] / sb), -128.f), 127.f) * sb;
    for (int m = threadIdx.x; m < 8192; m += 256) {
        const float sxm = s_x[m];
        float a = 0.f;
        for (int k = 0; k < 1024; ++k) {
            float q = nearbyintf(x[(size_t)m * 1024 + k] / sxm);
            a += fminf(fmaxf(q, -128.f), 127.f) * sxm * qw[k];
        }
        hbuf[(size_t)m * 4096 + n] = f2bf(gelu_exact(a + bq));
    }
}

// --------------------------- gemm2 + bias (256x128 tile) ---------------------
// grid (8, 32): x = N-block -> XCD = x (1 MB W2 panel L2-resident per XCD).
// 256 blocks, 1/CU, 96 KB LDS, 8-phase core, K=4096 (32 iterations).
__global__ __launch_bounds__(512, 2)
void gemm2_bias(const unsigned short* __restrict__ hbuf,
                const unsigned short* __restrict__ w2b,
                const float* __restrict__ b2,
                float* __restrict__ out)
{
    __shared__ unsigned short lds[49152];   // 96 KB: 2 tile buffers x 48 KB
    v4f acc[8][2];
    v4f z = {0.f, 0.f, 0.f, 0.f};
#pragma unroll
    for (int i = 0; i < 8; ++i)
#pragma unroll
        for (int j = 0; j < 2; ++j) acc[i][j] = z;

    const int bn0 = blockIdx.x * 128, bm0 = blockIdx.y * 256;
    const int tid = threadIdx.x;
    const int lane = tid & 63, wave = tid >> 6;
    const int wm = wave >> 2, wn = wave & 3, q = lane >> 4;

    gemm_core8p<8>(hbuf, w2b, 4096, bm0, bn0, lds, acc);

    float bvj[2];
#pragma unroll
    for (int nf = 0; nf < 2; ++nf) bvj[nf] = b2[bn0 + wn * 32 + nf * 16 + (lane & 15)];

    float* slabf = (float*)lds;             // 64 x 128 fp32 slab = 32 KB
#pragma unroll
    for (int p = 0; p < 4; ++p) {
        __syncthreads();
        if (wm == (p >> 1)) {
            const int mfb = (p & 1) * 4;
#pragma unroll
            for (int mfp = 0; mfp < 4; ++mfp)
#pragma unroll
                for (int nf = 0; nf < 2; ++nf) {
                    const int colq = wn * 32 + nf * 16 + (lane & 15);
#pragma unroll
                    for (int r = 0; r < 4; ++r)
                        slabf[(mfp * 16 + q * 4 + r) * 128 + colq] =
                            acc[mfb + mfp][nf][r] + bvj[nf];
                }
        }
        __syncthreads();
#pragma unroll
        for (int s = 0; s < 4; ++s) {
            const int idx = s * 512 + tid;           // 0..2047
            const int row = idx >> 5, ch = idx & 31; // 64 rows x 32 float4
            *(float4*)&out[(size_t)(bm0 + p * 64 + row) * 1024 + bn0 + ch * 4] =
                *(const float4*)&slabf[row * 128 + ch * 4];
        }
    }
}

// --------------------------- launch ----------------------------------------
extern "C" void kernel_launch(void* const* d_in, const int* in_sizes, int n_in,
                              void* d_out, int out_size, void* d_ws, size_t ws_size,
                              hipStream_t stream)
{
    const float* x  = (const float*)d_in[0];   // [4,2048,1024] fp32
    const float* W1 = (const float*)d_in[1];   // [4096,1024]
    const float* b1 = (const float*)d_in[2];   // [4096]
    const float* W2 = (const float*)d_in[3];   // [1024,4096]
    const float* b2 = (const float*)d_in[4];   // [1024]
    float* out = (float*)d_out;                // [4,2048,1024] fp32 (32 MB)

    // bf16 copies of x and W1 parked in d_out (dead until gemm2 writes it):
    unsigned short* xb  = (unsigned short*)d_out;                       // 16 MB
    unsigned short* w1b = (unsigned short*)d_out + (size_t)8192 * 1024; // 8 MB

    char* ws = (char*)d_ws;
    int*   counts = (int*)(ws + 0);                       // 16 KB
    float* s_x    = (float*)(ws + (64 << 10));            // 32 KB
    float* s_w    = (float*)(ws + (96 << 10));            // 16 KB
    float* s_b    = (float*)(ws + (112 << 10));           // 4 B
    unsigned short* xpad  = (unsigned short*)(ws + (1 << 20));   // 2 MB
    unsigned short* w1pad = (unsigned short*)(ws + (3 << 20));   // 1 MB
    unsigned short* w2b   = (unsigned short*)(ws + (4 << 20));   // 8 MB
    unsigned short* hbuf  = (unsigned short*)(ws + (12 << 20));  // 64 MB -> 76 MB total

    prep_kernel<<<16385, 256, 0, stream>>>(x, W1, W2, b1, xb, w1b, w2b,
                                           xpad, w1pad, s_x, s_w, s_b, counts);
    gemm1_topk<<<dim3(16, 32, 2), 512, 0, stream>>>(xb, w1b, xpad, w1pad, b1, hbuf, counts);
    fixup_kernel<<<4096, 256, 0, stream>>>(x, W1, b1, counts, s_x, s_w, s_b, hbuf);
    gemm2_bias<<<dim3(8, 32), 512, 0, stream>>>(hbuf, w2b, b2, out);
}